// Round 11
// baseline (436.346 us; speedup 1.0000x reference)
//
#include <hip/hip_runtime.h>
#include <stdint.h>

#define N_NODES  8192
#define HIDDEN   256
#define HEADS    4
#define HEAD_DIM 64
#define NUM_EDGES 4096
#define NUM_INC  65536
#define LN_EPS   1e-5f

typedef unsigned int uint_t;

// Inputs fp32 (verified r1->r3). OUTPUTS FP32 (reference dtype; the 8-round
// bit-identical failure was bf16-encoding fp32 outputs — r10 post-mortem).

// ---------------- ws layout (bytes), total ~1.17 MB ----------------
// zeroed region [0, ZERO_BYTES) via k_zero kernel:
#define OFF_SEGSUM   0        // float [4096*4]
#define OFF_SEGSIZE  65536    // int   [4096]
#define OFF_NODECNT  81920    // int   [8192]
#define OFF_NODEFILL 114688   // int   [8192]
#define OFF_EDGEFILL 147456   // int   [4096]
#define OFF_WNODE    163840   // float [8192]
#define ZERO_BYTES   196608
// non-zeroed (fully written before read):
#define OFF_VKH      196608   // float [256*4]  layout [k][h]
#define OFF_BL       200704   // float [4]
#define OFF_LOGIT    200960   // float [8192*4]
#define OFF_NODEPTR  332032   // int [8193]
#define OFF_EDGEPTR  365056   // int [4097]
#define OFF_NODEINC  381696   // int [65536]
#define OFF_EDGEMEM  643840   // int [65536]
#define OFF_ATTN     905984   // float [65536]

// K0: zero the atomic-accumulator region (d_ws is 0xAA-poisoned each replay)
__global__ __launch_bounds__(256) void k_zero(uint_t* __restrict__ w) {
    w[blockIdx.x * 256 + threadIdx.x] = 0u;
}

// K1: v[k][h] = sum_d ea[h,d]*Ww[h*64+d, k];  bl[h] = sum_d Wb[h*64+d]*ea[h,d]
__global__ __launch_bounds__(256) void k_fold(const float* __restrict__ Ww,
                                              const float* __restrict__ Wb,
                                              const float* __restrict__ ea,
                                              float* __restrict__ vkh,
                                              float* __restrict__ bl) {
    int k = threadIdx.x, h = blockIdx.x;
    float a = 0.f;
    for (int d = 0; d < HEAD_DIM; ++d)
        a += ea[h * HEAD_DIM + d] * Ww[(size_t)(h * HEAD_DIM + d) * HIDDEN + k];
    vkh[k * HEADS + h] = a;
    if (k == 0) {
        float b = 0.f;
        for (int d = 0; d < HEAD_DIM; ++d)
            b += Wb[h * HEAD_DIM + d] * ea[h * HEAD_DIM + d];
        bl[h] = b;
    }
}

// K2: logit[n][h] = x[n,:]·v[:,h] + bl[h].  Thread per (n,h).
__global__ __launch_bounds__(256) void k_logits(const float* __restrict__ x,
                                                const float* __restrict__ vkh,
                                                const float* __restrict__ bl,
                                                float* __restrict__ logit) {
    __shared__ float vs[HIDDEN * HEADS];
    __shared__ float bls[HEADS];
    int t = threadIdx.x;
    for (int j = t; j < HIDDEN * HEADS; j += 256) vs[j] = vkh[j];
    if (t < HEADS) bls[t] = bl[t];
    __syncthreads();
    int n = blockIdx.x * 64 + (t >> 2);
    int h = t & 3;
    const float* xr = x + (size_t)n * HIDDEN;
    float acc = bls[h];
    for (int k = 0; k < HIDDEN; ++k)
        acc += xr[k] * vs[k * HEADS + h];
    logit[n * HEADS + h] = acc;
}

// K3: seg_sum[e][h] += exp(logit[n][h]);  seg_size[e]++;  node_cnt[n]++
__global__ void k_pass1(const int* __restrict__ node_idx, const int* __restrict__ edge_idx,
                        const float* __restrict__ logit, float* __restrict__ seg_sum,
                        int* __restrict__ seg_size, int* __restrict__ node_cnt) {
    int i = blockIdx.x * 256 + threadIdx.x;
    int n = node_idx[i], e = edge_idx[i];
    #pragma unroll
    for (int h = 0; h < HEADS; ++h)
        atomicAdd(&seg_sum[e * HEADS + h], __expf(logit[n * HEADS + h]));
    atomicAdd(&seg_size[e], 1);
    atomicAdd(&node_cnt[n], 1);
}

// K4: exclusive scans (block 0: nodes, block 1: edges); serial-by-t0 combine
__global__ __launch_bounds__(256) void k_scan(const int* __restrict__ node_cnt, int* __restrict__ node_ptr,
                                              const int* __restrict__ seg_size, int* __restrict__ edge_ptr) {
    __shared__ int part[256];
    const int* cnt; int* ptr; int n;
    if (blockIdx.x == 0) { cnt = node_cnt; ptr = node_ptr; n = N_NODES; }
    else                 { cnt = seg_size; ptr = edge_ptr; n = NUM_EDGES; }
    int t = threadIdx.x, C = n / 256;
    int s = 0;
    for (int j = 0; j < C; ++j) s += cnt[t * C + j];
    part[t] = s;
    __syncthreads();
    if (t == 0) {
        int run = 0;
        for (int i = 0; i < 256; ++i) { int tmp = part[i]; part[i] = run; run += tmp; }
        ptr[n] = run;
    }
    __syncthreads();
    int run = part[t];
    for (int j = 0; j < C; ++j) { ptr[t * C + j] = run; run += cnt[t * C + j]; }
}

// K5: fill CSRs
__global__ void k_fill(const int* __restrict__ node_idx, const int* __restrict__ edge_idx,
                       const int* __restrict__ node_ptr, const int* __restrict__ edge_ptr,
                       int* __restrict__ node_fill, int* __restrict__ edge_fill,
                       int* __restrict__ node_inc, int* __restrict__ edge_mem) {
    int i = blockIdx.x * 256 + threadIdx.x;
    int n = node_idx[i], e = edge_idx[i];
    int p = node_ptr[n] + atomicAdd(&node_fill[n], 1);
    node_inc[p] = i;
    int q = edge_ptr[e] + atomicAdd(&edge_fill[e], 1);
    edge_mem[q] = n;
}

// K6: attn per incidence + per-node sum w_node
__global__ void k_attn(const int* __restrict__ node_idx, const int* __restrict__ edge_idx,
                       const float* __restrict__ logit, const float* __restrict__ seg_sum,
                       const int* __restrict__ seg_size, float* __restrict__ attn,
                       float* __restrict__ w_node) {
    int i = blockIdx.x * 256 + threadIdx.x;
    int e = edge_idx[i];
    float a = 0.f;
    if (seg_size[e] >= 2) {
        int n = node_idx[i];
        float s = 0.f;
        #pragma unroll
        for (int h = 0; h < HEADS; ++h)
            s += __expf(logit[n * HEADS + h]) / seg_sum[e * HEADS + h];
        a = 0.25f * s;
        atomicAdd(&w_node[n], a);
    }
    attn[i] = a;
}

// K7: out = LN( (w/clip(cnt,1))·x @ ow.T + ob ).  16 rows/block, fp32 out.
__global__ __launch_bounds__(256) void k_out(const float* __restrict__ x,
                                             const float* __restrict__ w_node,
                                             const int* __restrict__ node_cnt,
                                             const float* __restrict__ out_w,
                                             const float* __restrict__ out_b,
                                             float* __restrict__ out) {
    __shared__ float y[16][HIDDEN + 1];
    __shared__ float sr[16], mu_s[16], rs_s[16];
    int t = threadIdx.x;
    int R = blockIdx.x * 16;
    if (t < 16) {
        int n = R + t;
        int c = node_cnt[n]; if (c < 1) c = 1;
        sr[t] = w_node[n] / (float)c;
    }
    __syncthreads();
    #pragma unroll
    for (int r = 0; r < 16; ++r)
        y[r][t] = sr[r] * x[(size_t)(R + r) * HIDDEN + t];
    __syncthreads();
    float acc[16];
    float bias = out_b[t];
    #pragma unroll
    for (int r = 0; r < 16; ++r) acc[r] = bias;
    const float* wr = out_w + (size_t)t * HIDDEN;
    for (int j = 0; j < HIDDEN; ++j) {
        float w = wr[j];
        #pragma unroll
        for (int r = 0; r < 16; ++r) acc[r] += y[r][j] * w;
    }
    __syncthreads();
    #pragma unroll
    for (int r = 0; r < 16; ++r) y[r][t] = acc[r];
    __syncthreads();
    if (t < 16) {
        float m = 0.f;
        for (int j = 0; j < HIDDEN; ++j) m += y[t][j];
        m *= (1.0f / HIDDEN);
        float s2 = 0.f;
        for (int j = 0; j < HIDDEN; ++j) { float d = y[t][j] - m; s2 += d * d; }
        mu_s[t] = m;
        rs_s[t] = rsqrtf(s2 * (1.0f / HIDDEN) + LN_EPS);
    }
    __syncthreads();
    #pragma unroll
    for (int r = 0; r < 16; ++r)
        out[(size_t)(R + r) * HIDDEN + t] = (y[r][t] - mu_s[r]) * rs_s[r];
}

// K8: attention_weights row per block; LDS fp32 accumulate, float4 store.
__global__ __launch_bounds__(256) void k_aw(const float* __restrict__ attn,
                                            const int* __restrict__ node_ptr,
                                            const int* __restrict__ node_inc,
                                            const int* __restrict__ edge_ptr,
                                            const int* __restrict__ edge_mem,
                                            const int* __restrict__ edge_idx,
                                            float* __restrict__ AW) {
    __shared__ __align__(16) float row[N_NODES];   // 32 KB
    int t = threadIdx.x;
    int i = blockIdx.x;
    for (int c = t; c < N_NODES; c += 256) row[c] = 0.f;
    __syncthreads();
    int pb = node_ptr[i], pe = node_ptr[i + 1];
    for (int p = pb; p < pe; ++p) {          // block-uniform loop
        int m = node_inc[p];
        float a = attn[m];
        if (a != 0.f) {
            int e = edge_idx[m];
            int qb = edge_ptr[e], qe = edge_ptr[e + 1];
            for (int q = qb + t; q < qe; q += 256)
                atomicAdd(&row[edge_mem[q]], a);   // LDS atomic
        }
    }
    __syncthreads();
    if (t == 0) row[i] = 0.f;                 // zero diagonal
    __syncthreads();
    float4* dst = (float4*)(AW + (size_t)i * N_NODES);
    const float4* src = (const float4*)row;
    for (int c = t; c < N_NODES / 4; c += 256)
        dst[c] = src[c];
}

extern "C" void kernel_launch(void* const* d_in, const int* in_sizes, int n_in,
                              void* d_out, int out_size, void* d_ws, size_t ws_size,
                              hipStream_t stream) {
    const float* x        = (const float*)d_in[0];
    const int*   node_idx = (const int*)d_in[1];
    const int*   edge_idx = (const int*)d_in[2];
    const float* Ww       = (const float*)d_in[3];
    const float* Wb       = (const float*)d_in[4];
    const float* ea       = (const float*)d_in[5];
    const float* ow       = (const float*)d_in[6];
    const float* ob       = (const float*)d_in[7];
    float* out0 = (float*)d_out;                         // fp32!
    float* aw   = out0 + (size_t)N_NODES * HIDDEN;       // fp32, 256 MB

    char* ws = (char*)d_ws;
    float* seg_sum   = (float*)(ws + OFF_SEGSUM);
    int*   seg_size  = (int*)(ws + OFF_SEGSIZE);
    int*   node_cnt  = (int*)(ws + OFF_NODECNT);
    int*   node_fill = (int*)(ws + OFF_NODEFILL);
    int*   edge_fill = (int*)(ws + OFF_EDGEFILL);
    float* w_node    = (float*)(ws + OFF_WNODE);
    float* vkh       = (float*)(ws + OFF_VKH);
    float* bl        = (float*)(ws + OFF_BL);
    float* logit     = (float*)(ws + OFF_LOGIT);
    int*   node_ptr  = (int*)(ws + OFF_NODEPTR);
    int*   edge_ptr  = (int*)(ws + OFF_EDGEPTR);
    int*   node_inc  = (int*)(ws + OFF_NODEINC);
    int*   edge_mem  = (int*)(ws + OFF_EDGEMEM);
    float* attn      = (float*)(ws + OFF_ATTN);

    k_zero<<<ZERO_BYTES / 4 / 256, 256, 0, stream>>>((uint_t*)ws);
    k_fold<<<HEADS, 256, 0, stream>>>(Ww, Wb, ea, vkh, bl);
    k_logits<<<N_NODES / 64, 256, 0, stream>>>(x, vkh, bl, logit);
    k_pass1<<<NUM_INC / 256, 256, 0, stream>>>(node_idx, edge_idx, logit, seg_sum, seg_size, node_cnt);
    k_scan<<<2, 256, 0, stream>>>(node_cnt, node_ptr, seg_size, edge_ptr);
    k_fill<<<NUM_INC / 256, 256, 0, stream>>>(node_idx, edge_idx, node_ptr, edge_ptr,
                                              node_fill, edge_fill, node_inc, edge_mem);
    k_attn<<<NUM_INC / 256, 256, 0, stream>>>(node_idx, edge_idx, logit, seg_sum, seg_size, attn, w_node);
    k_out<<<N_NODES / 16, 256, 0, stream>>>(x, w_node, node_cnt, ow, ob, out0);
    k_aw<<<N_NODES, 256, 0, stream>>>(attn, node_ptr, node_inc, edge_ptr, edge_mem, edge_idx, aw);
}

// Round 12
// 398.185 us; speedup vs baseline: 1.0958x; 1.0958x over previous
//
#include <hip/hip_runtime.h>
#include <stdint.h>

#define N_NODES  8192
#define HIDDEN   256
#define HEADS    4
#define HEAD_DIM 64
#define NUM_EDGES 4096
#define NUM_INC  65536
#define LN_EPS   1e-5f

typedef unsigned int uint_t;

// Inputs fp32, OUTPUTS fp32 (r11 verified: passed 436us, absmax 0.0156).

// ---------------- ws layout (bytes), end 1134688 < r11-proven 1168128 ----------
// zeroed [0, ZERO_BYTES) via k_zero (d_ws is 0xAA-poisoned before each replay):
#define OFF_SEGSZ    0        // int [4096]
#define OFF_NCNT     16384    // int [8192]
#define OFF_NFILL    49152    // int [8192]
#define OFF_EFILL    81920    // int [4096]
#define ZERO_BYTES   98304
// non-zeroed (fully written before read):
#define OFF_VKH      98304    // float [256*4] transposed: [h][k]
#define OFF_BL       102400   // float [pad]
#define OFF_LOGIT    102464   // float [8192*4]
#define OFF_NPTR     233536   // int [8193] (+pad)
#define OFF_EPTR     266320   // int [4097] (+pad)
#define OFF_SEGSUM   282720   // float [4096*4]
#define OFF_NINC     348256   // int [65536]
#define OFF_EMEM     610400   // int [65536]
#define OFF_ATTN     872544   // float [65536]

// K0: zero count accumulators. 96 blocks.
__global__ __launch_bounds__(256) void k_zero(uint_t* __restrict__ w) {
    w[blockIdx.x * 256 + threadIdx.x] = 0u;
}

// K1: vkhT[h][k] = sum_d ea[h,d]*Ww[h*64+d, k];  bl[h] likewise with Wb.
__global__ __launch_bounds__(256) void k_fold(const float* __restrict__ Ww,
                                              const float* __restrict__ Wb,
                                              const float* __restrict__ ea,
                                              float* __restrict__ vkhT,
                                              float* __restrict__ bl) {
    int k = threadIdx.x, h = blockIdx.x;
    float a = 0.f;
    for (int d = 0; d < HEAD_DIM; ++d)
        a += ea[h * HEAD_DIM + d] * Ww[(size_t)(h * HEAD_DIM + d) * HIDDEN + k];
    vkhT[h * HIDDEN + k] = a;                  // [h][k] layout for float4 reads
    if (k == 0) {
        float b = 0.f;
        for (int d = 0; d < HEAD_DIM; ++d)
            b += Wb[h * HEAD_DIM + d] * ea[h * HEAD_DIM + d];
        bl[h] = b;
    }
}

// K2: logits. 256 blocks x 32 nodes; x staged to LDS coalesced.
__global__ __launch_bounds__(256) void k_logits(const float* __restrict__ x,
                                                const float* __restrict__ vkhT,
                                                const float* __restrict__ bl,
                                                float* __restrict__ logit) {
    __shared__ __align__(16) float xs[32 * HIDDEN];    // 32 KB
    __shared__ __align__(16) float vs[HEADS * HIDDEN]; // 4 KB, [h][k]
    __shared__ float bls[HEADS];
    int t = threadIdx.x, b = blockIdx.x;
    float4* xsv = (float4*)xs;
    const float4* xg = (const float4*)(x + (size_t)b * 32 * HIDDEN);
    #pragma unroll
    for (int i = 0; i < 8; ++i) xsv[i * 256 + t] = xg[i * 256 + t];
    ((float4*)vs)[t] = ((const float4*)vkhT)[t];
    if (t < HEADS) bls[t] = bl[t];
    __syncthreads();
    if (t < 128) {
        int n = t >> 2, h = t & 3;
        const float4* xr = (const float4*)(xs + n * HIDDEN);
        const float4* vr = (const float4*)(vs + h * HIDDEN);
        float acc = bls[h];
        for (int k4 = 0; k4 < HIDDEN / 4; ++k4) {
            float4 xv = xr[k4], vv = vr[k4];
            acc += xv.x * vv.x + xv.y * vv.y + xv.z * vv.z + xv.w * vv.w;
        }
        logit[(b * 32 + n) * HEADS + h] = acc;
    }
}

// K3: histogram counts only (int atomics)
__global__ void k_pass1(const int* __restrict__ node_idx, const int* __restrict__ edge_idx,
                        int* __restrict__ seg_size, int* __restrict__ node_cnt) {
    int i = blockIdx.x * 256 + threadIdx.x;
    atomicAdd(&seg_size[edge_idx[i]], 1);
    atomicAdd(&node_cnt[node_idx[i]], 1);
}

// K4: exclusive scans (block 0: nodes, block 1: edges)
__global__ __launch_bounds__(256) void k_scan(const int* __restrict__ node_cnt, int* __restrict__ node_ptr,
                                              const int* __restrict__ seg_size, int* __restrict__ edge_ptr) {
    __shared__ int part[256];
    const int* cnt; int* ptr; int n;
    if (blockIdx.x == 0) { cnt = node_cnt; ptr = node_ptr; n = N_NODES; }
    else                 { cnt = seg_size; ptr = edge_ptr; n = NUM_EDGES; }
    int t = threadIdx.x, C = n / 256;
    int s = 0;
    for (int j = 0; j < C; ++j) s += cnt[t * C + j];
    part[t] = s;
    __syncthreads();
    if (t == 0) {
        int run = 0;
        for (int i = 0; i < 256; ++i) { int tmp = part[i]; part[i] = run; run += tmp; }
        ptr[n] = run;
    }
    __syncthreads();
    int run = part[t];
    for (int j = 0; j < C; ++j) { ptr[t * C + j] = run; run += cnt[t * C + j]; }
}

// K5: fill CSRs
__global__ void k_fill(const int* __restrict__ node_idx, const int* __restrict__ edge_idx,
                       const int* __restrict__ node_ptr, const int* __restrict__ edge_ptr,
                       int* __restrict__ node_fill, int* __restrict__ edge_fill,
                       int* __restrict__ node_inc, int* __restrict__ edge_mem) {
    int i = blockIdx.x * 256 + threadIdx.x;
    int n = node_idx[i], e = edge_idx[i];
    int p = node_ptr[n] + atomicAdd(&node_fill[n], 1);
    node_inc[p] = i;
    int q = edge_ptr[e] + atomicAdd(&edge_fill[e], 1);
    edge_mem[q] = n;
}

// K6: seg_sum by edge-parallel gather (no fp32 atomics)
__global__ __launch_bounds__(256) void k_seg(const int* __restrict__ edge_ptr,
                                             const int* __restrict__ edge_mem,
                                             const float* __restrict__ logit,
                                             float* __restrict__ seg_sum) {
    int e = blockIdx.x * 256 + threadIdx.x;
    int qb = edge_ptr[e], qe = edge_ptr[e + 1];
    float s0 = 0, s1 = 0, s2 = 0, s3 = 0;
    for (int q = qb; q < qe; ++q) {
        int j = edge_mem[q];
        s0 += __expf(logit[j * 4 + 0]);
        s1 += __expf(logit[j * 4 + 1]);
        s2 += __expf(logit[j * 4 + 2]);
        s3 += __expf(logit[j * 4 + 3]);
    }
    seg_sum[e * 4 + 0] = s0; seg_sum[e * 4 + 1] = s1;
    seg_sum[e * 4 + 2] = s2; seg_sum[e * 4 + 3] = s3;
}

// K7: attn per incidence (no w_node atomics; sr derived from CSR in k_out)
__global__ void k_attn(const int* __restrict__ node_idx, const int* __restrict__ edge_idx,
                       const float* __restrict__ logit, const float* __restrict__ seg_sum,
                       const int* __restrict__ seg_size, float* __restrict__ attn) {
    int i = blockIdx.x * 256 + threadIdx.x;
    int e = edge_idx[i];
    float a = 0.f;
    if (seg_size[e] >= 2) {
        int n = node_idx[i];
        float s = 0.f;
        #pragma unroll
        for (int h = 0; h < HEADS; ++h)
            s += __expf(logit[n * HEADS + h]) / seg_sum[e * HEADS + h];
        a = 0.25f * s;
    }
    attn[i] = a;
}

// K8: out = LN( sr*x @ ow.T + ob ). 16 rows/block, float4 inner loop.
__global__ __launch_bounds__(256) void k_out(const float* __restrict__ x,
                                             const int* __restrict__ node_ptr,
                                             const int* __restrict__ node_inc,
                                             const float* __restrict__ attn,
                                             const float* __restrict__ out_w,
                                             const float* __restrict__ out_b,
                                             float* __restrict__ out) {
    __shared__ __align__(16) float y[16][260];          // 260: 16B-aligned rows
    __shared__ float sr[16], mu_s[16], rs_s[16];
    int t = threadIdx.x;
    int R = blockIdx.x * 16;
    if (t < 16) {
        int n = R + t;
        int pb = node_ptr[n], pe = node_ptr[n + 1];
        float w = 0.f;
        for (int p = pb; p < pe; ++p) w += attn[node_inc[p]];
        int c = pe - pb; if (c < 1) c = 1;
        sr[t] = w / (float)c;
    }
    __syncthreads();
    #pragma unroll
    for (int r = 0; r < 16; ++r)
        y[r][t] = sr[r] * x[(size_t)(R + r) * HIDDEN + t];   // coalesced
    __syncthreads();
    float acc[16];
    float bias = out_b[t];
    #pragma unroll
    for (int r = 0; r < 16; ++r) acc[r] = bias;
    const float4* wr4 = (const float4*)(out_w + (size_t)t * HIDDEN);
    for (int j4 = 0; j4 < HIDDEN / 4; ++j4) {
        float4 wv = wr4[j4];
        #pragma unroll
        for (int r = 0; r < 16; ++r) {
            float4 yv = *(const float4*)&y[r][j4 * 4];       // broadcast b128
            acc[r] += yv.x * wv.x + yv.y * wv.y + yv.z * wv.z + yv.w * wv.w;
        }
    }
    __syncthreads();
    #pragma unroll
    for (int r = 0; r < 16; ++r) y[r][t] = acc[r];
    __syncthreads();
    if (t < 16) {
        float m = 0.f;
        for (int j = 0; j < HIDDEN; ++j) m += y[t][j];
        m *= (1.0f / HIDDEN);
        float s2 = 0.f;
        for (int j = 0; j < HIDDEN; ++j) { float d = y[t][j] - m; s2 += d * d; }
        mu_s[t] = m;
        rs_s[t] = rsqrtf(s2 * (1.0f / HIDDEN) + LN_EPS);
    }
    __syncthreads();
    #pragma unroll
    for (int r = 0; r < 16; ++r)
        out[(size_t)(R + r) * HIDDEN + t] = (y[r][t] - mu_s[r]) * rs_s[r];
}

// K9: AW row per block. Wave-parallel p-loop (4 chains), float4 init/store.
__global__ __launch_bounds__(256) void k_aw(const float* __restrict__ attn,
                                            const int* __restrict__ node_ptr,
                                            const int* __restrict__ node_inc,
                                            const int* __restrict__ edge_ptr,
                                            const int* __restrict__ edge_mem,
                                            const int* __restrict__ edge_idx,
                                            float* __restrict__ AW) {
    __shared__ __align__(16) float row[N_NODES];   // 32 KB
    int t = threadIdx.x, w = t >> 6, lane = t & 63;
    int i = blockIdx.x;
    float4* rowv = (float4*)row;
    #pragma unroll
    for (int c = 0; c < 8; ++c) rowv[c * 256 + t] = make_float4(0.f, 0.f, 0.f, 0.f);
    __syncthreads();
    int pb = node_ptr[i], pe = node_ptr[i + 1];
    for (int p = pb + w; p < pe; p += 4) {         // wave-uniform, 4 parallel chains
        int m = node_inc[p];
        float a = attn[m];
        if (a != 0.f) {
            int e = edge_idx[m];
            int qb = edge_ptr[e], qe = edge_ptr[e + 1];
            for (int q = qb + lane; q < qe; q += 64)
                atomicAdd(&row[edge_mem[q]], a);   // LDS atomic
        }
    }
    __syncthreads();
    if (t == 0) row[i] = 0.f;                      // zero diagonal
    __syncthreads();
    float4* dst = (float4*)(AW + (size_t)i * N_NODES);
    #pragma unroll
    for (int c = 0; c < 8; ++c) dst[c * 256 + t] = rowv[c * 256 + t];
}

extern "C" void kernel_launch(void* const* d_in, const int* in_sizes, int n_in,
                              void* d_out, int out_size, void* d_ws, size_t ws_size,
                              hipStream_t stream) {
    const float* x        = (const float*)d_in[0];
    const int*   node_idx = (const int*)d_in[1];
    const int*   edge_idx = (const int*)d_in[2];
    const float* Ww       = (const float*)d_in[3];
    const float* Wb       = (const float*)d_in[4];
    const float* ea       = (const float*)d_in[5];
    const float* ow       = (const float*)d_in[6];
    const float* ob       = (const float*)d_in[7];
    float* out0 = (float*)d_out;
    float* aw   = out0 + (size_t)N_NODES * HIDDEN;

    char* ws = (char*)d_ws;
    int*   seg_size  = (int*)(ws + OFF_SEGSZ);
    int*   node_cnt  = (int*)(ws + OFF_NCNT);
    int*   node_fill = (int*)(ws + OFF_NFILL);
    int*   edge_fill = (int*)(ws + OFF_EFILL);
    float* vkhT      = (float*)(ws + OFF_VKH);
    float* bl        = (float*)(ws + OFF_BL);
    float* logit     = (float*)(ws + OFF_LOGIT);
    int*   node_ptr  = (int*)(ws + OFF_NPTR);
    int*   edge_ptr  = (int*)(ws + OFF_EPTR);
    float* seg_sum   = (float*)(ws + OFF_SEGSUM);
    int*   node_inc  = (int*)(ws + OFF_NINC);
    int*   edge_mem  = (int*)(ws + OFF_EMEM);
    float* attn      = (float*)(ws + OFF_ATTN);

    k_zero<<<ZERO_BYTES / 4 / 256, 256, 0, stream>>>((uint_t*)ws);
    k_fold<<<HEADS, 256, 0, stream>>>(Ww, Wb, ea, vkhT, bl);
    k_logits<<<N_NODES / 32, 256, 0, stream>>>(x, vkhT, bl, logit);
    k_pass1<<<NUM_INC / 256, 256, 0, stream>>>(node_idx, edge_idx, seg_size, node_cnt);
    k_scan<<<2, 256, 0, stream>>>(node_cnt, node_ptr, seg_size, edge_ptr);
    k_fill<<<NUM_INC / 256, 256, 0, stream>>>(node_idx, edge_idx, node_ptr, edge_ptr,
                                              node_fill, edge_fill, node_inc, edge_mem);
    k_seg<<<NUM_EDGES / 256, 256, 0, stream>>>(edge_ptr, edge_mem, logit, seg_sum);
    k_attn<<<NUM_INC / 256, 256, 0, stream>>>(node_idx, edge_idx, logit, seg_sum, seg_size, attn);
    k_out<<<N_NODES / 16, 256, 0, stream>>>(x, node_ptr, node_inc, attn, ow, ob, out0);
    k_aw<<<N_NODES, 256, 0, stream>>>(attn, node_ptr, node_inc, edge_ptr, edge_mem, edge_idx, aw);
}

// Round 13
// 397.108 us; speedup vs baseline: 1.0988x; 1.0027x over previous
//
#include <hip/hip_runtime.h>
#include <stdint.h>

#define N_NODES  8192
#define HIDDEN   256
#define HEADS    4
#define HEAD_DIM 64
#define NUM_EDGES 4096
#define NUM_INC  65536
#define LN_EPS   1e-5f

typedef unsigned int uint_t;
typedef float __attribute__((ext_vector_type(4))) f4v;

// Inputs fp32, OUTPUTS fp32 (r11/r12 verified). ws_size ~1.08 GB (poison fill
// evidence, r12 counters) — 1.92 MB layout is safe.

// ---------------- ws layout (bytes) ----------------
// zeroed [0, ZERO_BYTES) via k_zero:
#define OFF_SEGSZ    0        // int [4096]
#define OFF_NCNT     16384    // int [8192]
#define OFF_NFILL    49152    // int [8192]
#define OFF_EFILL    81920    // int [4096]
#define ZERO_BYTES   98304
// non-zeroed (fully written before read):
#define OFF_VKH      98304    // float [4*256] transposed [h][k]
#define OFF_BL       102400   // float [pad]
#define OFF_LOGIT    102464   // float [8192*4]
#define OFF_NPTR     233536   // int [8193] (+pad)
#define OFF_EPTR     266320   // int [4097] (+pad)
#define OFF_SEGSUM   282720   // float [4096*4]
#define OFF_NINC     348256   // int [65536]
#define OFF_EMEM     610400   // int [65536]
#define OFF_ITEM     872544   // float4 [65536] = {attn, qb(bits), qe(bits), 0}  (1 MB; end 1921120)

// K0: zero count accumulators (d_ws is 0xAA-poisoned before each replay)
__global__ __launch_bounds__(256) void k_zero(uint_t* __restrict__ w) {
    w[blockIdx.x * 256 + threadIdx.x] = 0u;
}

// K1: vkhT[h][k] = sum_d ea[h,d]*Ww[h*64+d, k];  bl[h] likewise with Wb.
__global__ __launch_bounds__(256) void k_fold(const float* __restrict__ Ww,
                                              const float* __restrict__ Wb,
                                              const float* __restrict__ ea,
                                              float* __restrict__ vkhT,
                                              float* __restrict__ bl) {
    int k = threadIdx.x, h = blockIdx.x;
    float a = 0.f;
    for (int d = 0; d < HEAD_DIM; ++d)
        a += ea[h * HEAD_DIM + d] * Ww[(size_t)(h * HEAD_DIM + d) * HIDDEN + k];
    vkhT[h * HIDDEN + k] = a;
    if (k == 0) {
        float b = 0.f;
        for (int d = 0; d < HEAD_DIM; ++d)
            b += Wb[h * HEAD_DIM + d] * ea[h * HEAD_DIM + d];
        bl[h] = b;
    }
}

// K2: logits. 256 blocks x 32 nodes; x staged to LDS coalesced.
__global__ __launch_bounds__(256) void k_logits(const float* __restrict__ x,
                                                const float* __restrict__ vkhT,
                                                const float* __restrict__ bl,
                                                float* __restrict__ logit) {
    __shared__ __align__(16) float xs[32 * HIDDEN];
    __shared__ __align__(16) float vs[HEADS * HIDDEN];
    __shared__ float bls[HEADS];
    int t = threadIdx.x, b = blockIdx.x;
    float4* xsv = (float4*)xs;
    const float4* xg = (const float4*)(x + (size_t)b * 32 * HIDDEN);
    #pragma unroll
    for (int i = 0; i < 8; ++i) xsv[i * 256 + t] = xg[i * 256 + t];
    ((float4*)vs)[t] = ((const float4*)vkhT)[t];
    if (t < HEADS) bls[t] = bl[t];
    __syncthreads();
    if (t < 128) {
        int n = t >> 2, h = t & 3;
        const float4* xr = (const float4*)(xs + n * HIDDEN);
        const float4* vr = (const float4*)(vs + h * HIDDEN);
        float acc = bls[h];
        for (int k4 = 0; k4 < HIDDEN / 4; ++k4) {
            float4 xv = xr[k4], vv = vr[k4];
            acc += xv.x * vv.x + xv.y * vv.y + xv.z * vv.z + xv.w * vv.w;
        }
        logit[(b * 32 + n) * HEADS + h] = acc;
    }
}

// K3: histogram counts (int atomics)
__global__ void k_pass1(const int* __restrict__ node_idx, const int* __restrict__ edge_idx,
                        int* __restrict__ seg_size, int* __restrict__ node_cnt) {
    int i = blockIdx.x * 256 + threadIdx.x;
    atomicAdd(&seg_size[edge_idx[i]], 1);
    atomicAdd(&node_cnt[node_idx[i]], 1);
}

// K4: exclusive scans
__global__ __launch_bounds__(256) void k_scan(const int* __restrict__ node_cnt, int* __restrict__ node_ptr,
                                              const int* __restrict__ seg_size, int* __restrict__ edge_ptr) {
    __shared__ int part[256];
    const int* cnt; int* ptr; int n;
    if (blockIdx.x == 0) { cnt = node_cnt; ptr = node_ptr; n = N_NODES; }
    else                 { cnt = seg_size; ptr = edge_ptr; n = NUM_EDGES; }
    int t = threadIdx.x, C = n / 256;
    int s = 0;
    for (int j = 0; j < C; ++j) s += cnt[t * C + j];
    part[t] = s;
    __syncthreads();
    if (t == 0) {
        int run = 0;
        for (int i = 0; i < 256; ++i) { int tmp = part[i]; part[i] = run; run += tmp; }
        ptr[n] = run;
    }
    __syncthreads();
    int run = part[t];
    for (int j = 0; j < C; ++j) { ptr[t * C + j] = run; run += cnt[t * C + j]; }
}

// K5: fill CSRs
__global__ void k_fill(const int* __restrict__ node_idx, const int* __restrict__ edge_idx,
                       const int* __restrict__ node_ptr, const int* __restrict__ edge_ptr,
                       int* __restrict__ node_fill, int* __restrict__ edge_fill,
                       int* __restrict__ node_inc, int* __restrict__ edge_mem) {
    int i = blockIdx.x * 256 + threadIdx.x;
    int n = node_idx[i], e = edge_idx[i];
    int p = node_ptr[n] + atomicAdd(&node_fill[n], 1);
    node_inc[p] = i;
    int q = edge_ptr[e] + atomicAdd(&edge_fill[e], 1);
    edge_mem[q] = n;
}

// K6: seg_sum by edge-parallel gather
__global__ __launch_bounds__(256) void k_seg(const int* __restrict__ edge_ptr,
                                             const int* __restrict__ edge_mem,
                                             const float* __restrict__ logit,
                                             float* __restrict__ seg_sum) {
    int e = blockIdx.x * 256 + threadIdx.x;
    int qb = edge_ptr[e], qe = edge_ptr[e + 1];
    float s0 = 0, s1 = 0, s2 = 0, s3 = 0;
    for (int q = qb; q < qe; ++q) {
        int j = edge_mem[q];
        s0 += __expf(logit[j * 4 + 0]);
        s1 += __expf(logit[j * 4 + 1]);
        s2 += __expf(logit[j * 4 + 2]);
        s3 += __expf(logit[j * 4 + 3]);
    }
    seg_sum[e * 4 + 0] = s0; seg_sum[e * 4 + 1] = s1;
    seg_sum[e * 4 + 2] = s2; seg_sum[e * 4 + 3] = s3;
}

// K7: aw_item[p] = {attn, qb, qe, 0} in node-CSR order (replaces k_attn).
// Shortens k_aw's chain to item->edge_mem and makes k_out's sr-sum contiguous.
__global__ __launch_bounds__(256) void k_pairs(const int* __restrict__ node_inc,
                                               const int* __restrict__ node_idx,
                                               const int* __restrict__ edge_idx,
                                               const int* __restrict__ edge_ptr,
                                               const float* __restrict__ logit,
                                               const float* __restrict__ seg_sum,
                                               float4* __restrict__ item) {
    int p = blockIdx.x * 256 + threadIdx.x;
    int m = node_inc[p];
    int e = edge_idx[m];
    int qb = edge_ptr[e], qe = edge_ptr[e + 1];
    float a = 0.f;
    if (qe - qb >= 2) {
        int n = node_idx[m];
        float s = 0.f;
        #pragma unroll
        for (int h = 0; h < HEADS; ++h)
            s += __expf(logit[n * HEADS + h]) / seg_sum[e * HEADS + h];
        a = 0.25f * s;
    }
    float4 it;
    it.x = a;
    it.y = __int_as_float(qb);
    it.z = __int_as_float(qe);
    it.w = 0.f;
    item[p] = it;
}

// K8: out = LN( sr*x @ ow.T + ob ). 16 rows/block, float4 inner loop.
__global__ __launch_bounds__(256) void k_out(const float* __restrict__ x,
                                             const int* __restrict__ node_ptr,
                                             const float4* __restrict__ item,
                                             const float* __restrict__ out_w,
                                             const float* __restrict__ out_b,
                                             float* __restrict__ out) {
    __shared__ __align__(16) float y[16][260];
    __shared__ float sr[16], mu_s[16], rs_s[16];
    int t = threadIdx.x;
    int R = blockIdx.x * 16;
    if (t < 16) {
        int n = R + t;
        int pb = node_ptr[n], pe = node_ptr[n + 1];
        float w = 0.f;
        for (int p = pb; p < pe; ++p) w += item[p].x;   // contiguous
        int c = pe - pb; if (c < 1) c = 1;
        sr[t] = w / (float)c;
    }
    __syncthreads();
    #pragma unroll
    for (int r = 0; r < 16; ++r)
        y[r][t] = sr[r] * x[(size_t)(R + r) * HIDDEN + t];
    __syncthreads();
    float acc[16];
    float bias = out_b[t];
    #pragma unroll
    for (int r = 0; r < 16; ++r) acc[r] = bias;
    const float4* wr4 = (const float4*)(out_w + (size_t)t * HIDDEN);
    for (int j4 = 0; j4 < HIDDEN / 4; ++j4) {
        float4 wv = wr4[j4];
        #pragma unroll
        for (int r = 0; r < 16; ++r) {
            float4 yv = *(const float4*)&y[r][j4 * 4];
            acc[r] += yv.x * wv.x + yv.y * wv.y + yv.z * wv.z + yv.w * wv.w;
        }
    }
    __syncthreads();
    #pragma unroll
    for (int r = 0; r < 16; ++r) y[r][t] = acc[r];
    __syncthreads();
    if (t < 16) {
        float m = 0.f;
        for (int j = 0; j < HIDDEN; ++j) m += y[t][j];
        m *= (1.0f / HIDDEN);
        float s2 = 0.f;
        for (int j = 0; j < HIDDEN; ++j) { float d = y[t][j] - m; s2 += d * d; }
        mu_s[t] = m;
        rs_s[t] = rsqrtf(s2 * (1.0f / HIDDEN) + LN_EPS);
    }
    __syncthreads();
    #pragma unroll
    for (int r = 0; r < 16; ++r)
        out[(size_t)(R + r) * HIDDEN + t] = (y[r][t] - mu_s[r]) * rs_s[r];
}

// K9: AW row per block. 2-deep chain (item -> edge_mem), nt float4 stores.
__global__ __launch_bounds__(256) void k_aw(const float4* __restrict__ item,
                                            const int* __restrict__ node_ptr,
                                            const int* __restrict__ edge_mem,
                                            float* __restrict__ AW) {
    __shared__ __align__(16) float row[N_NODES];   // 32 KB
    int t = threadIdx.x, w = t >> 6, lane = t & 63;
    int i = blockIdx.x;
    float4* rowv = (float4*)row;
    #pragma unroll
    for (int c = 0; c < 8; ++c) rowv[c * 256 + t] = make_float4(0.f, 0.f, 0.f, 0.f);
    __syncthreads();
    int pb = node_ptr[i], pe = node_ptr[i + 1];
    for (int p = pb + w; p < pe; p += 4) {         // 4 parallel wave chains
        float4 it = item[p];
        float a = it.x;
        if (a != 0.f) {
            int qb = __float_as_int(it.y), qe = __float_as_int(it.z);
            for (int q = qb + lane; q < qe; q += 64)
                atomicAdd(&row[edge_mem[q]], a);   // LDS atomic
        }
    }
    __syncthreads();
    if (t == 0) row[i] = 0.f;                      // zero diagonal
    __syncthreads();
    f4v* dst = (f4v*)(AW + (size_t)i * N_NODES);
    const f4v* src = (const f4v*)row;
    #pragma unroll
    for (int c = 0; c < 8; ++c)
        __builtin_nontemporal_store(src[c * 256 + t], &dst[c * 256 + t]);
}

extern "C" void kernel_launch(void* const* d_in, const int* in_sizes, int n_in,
                              void* d_out, int out_size, void* d_ws, size_t ws_size,
                              hipStream_t stream) {
    const float* x        = (const float*)d_in[0];
    const int*   node_idx = (const int*)d_in[1];
    const int*   edge_idx = (const int*)d_in[2];
    const float* Ww       = (const float*)d_in[3];
    const float* Wb       = (const float*)d_in[4];
    const float* ea       = (const float*)d_in[5];
    const float* ow       = (const float*)d_in[6];
    const float* ob       = (const float*)d_in[7];
    float* out0 = (float*)d_out;
    float* aw   = out0 + (size_t)N_NODES * HIDDEN;

    char* ws = (char*)d_ws;
    int*    seg_size  = (int*)(ws + OFF_SEGSZ);
    int*    node_cnt  = (int*)(ws + OFF_NCNT);
    int*    node_fill = (int*)(ws + OFF_NFILL);
    int*    edge_fill = (int*)(ws + OFF_EFILL);
    float*  vkhT      = (float*)(ws + OFF_VKH);
    float*  bl        = (float*)(ws + OFF_BL);
    float*  logit     = (float*)(ws + OFF_LOGIT);
    int*    node_ptr  = (int*)(ws + OFF_NPTR);
    int*    edge_ptr  = (int*)(ws + OFF_EPTR);
    float*  seg_sum   = (float*)(ws + OFF_SEGSUM);
    int*    node_inc  = (int*)(ws + OFF_NINC);
    int*    edge_mem  = (int*)(ws + OFF_EMEM);
    float4* item      = (float4*)(ws + OFF_ITEM);

    k_zero<<<ZERO_BYTES / 4 / 256, 256, 0, stream>>>((uint_t*)ws);
    k_fold<<<HEADS, 256, 0, stream>>>(Ww, Wb, ea, vkhT, bl);
    k_logits<<<N_NODES / 32, 256, 0, stream>>>(x, vkhT, bl, logit);
    k_pass1<<<NUM_INC / 256, 256, 0, stream>>>(node_idx, edge_idx, seg_size, node_cnt);
    k_scan<<<2, 256, 0, stream>>>(node_cnt, node_ptr, seg_size, edge_ptr);
    k_fill<<<NUM_INC / 256, 256, 0, stream>>>(node_idx, edge_idx, node_ptr, edge_ptr,
                                              node_fill, edge_fill, node_inc, edge_mem);
    k_seg<<<NUM_EDGES / 256, 256, 0, stream>>>(edge_ptr, edge_mem, logit, seg_sum);
    k_pairs<<<NUM_INC / 256, 256, 0, stream>>>(node_inc, node_idx, edge_idx, edge_ptr,
                                               logit, seg_sum, item);
    k_out<<<N_NODES / 16, 256, 0, stream>>>(x, node_ptr, item, ow, ob, out0);
    k_aw<<<N_NODES, 256, 0, stream>>>(item, node_ptr, edge_mem, aw);
}

// Round 14
// 368.313 us; speedup vs baseline: 1.1847x; 1.0782x over previous
//
#include <hip/hip_runtime.h>
#include <stdint.h>

#define N_NODES  8192
#define HIDDEN   256
#define HEADS    4
#define HEAD_DIM 64
#define NUM_EDGES 4096
#define NUM_INC  65536
#define LN_EPS   1e-5f

typedef unsigned int uint_t;
typedef float __attribute__((ext_vector_type(4))) f4v;

// Inputs fp32, OUTPUTS fp32 (r11-r13 verified, absmax 0.0156).
// r13 model: ~225us/replay is harness poison/restore; kernel share ~170us.
// This round: fuse k_out into k_aw (pipe overlap), merge k_zero into k_fold,
// wave-parallel LN. 12 -> 8 dispatches.

// ---------------- ws layout (bytes) ----------------
#define OFF_SEGSZ    0        // int [4096]   } zeroed by k_foldzero
#define OFF_NCNT     16384    // int [8192]   }
#define OFF_NFILL    49152    // int [8192]   }
#define OFF_EFILL    81920    // int [4096]   }
#define ZERO_BYTES   98304
#define OFF_VKH      98304    // float [4*256] transposed [h][k]
#define OFF_BL       102400   // float [pad]
#define OFF_LOGIT    102464   // float [8192*4]
#define OFF_NPTR     233536   // int [8193] (+pad)
#define OFF_EPTR     266320   // int [4097] (+pad)
#define OFF_SEGSUM   282720   // float [4096*4]
#define OFF_NINC     348256   // int [65536]
#define OFF_EMEM     610400   // int [65536]
#define OFF_ITEM     872544   // float4 [65536] = {attn, qb, qe, 0}

// K1: zero accumulators (96 blocks); blocks 0..3 also fold W_w/W_b with ea.
__global__ __launch_bounds__(256) void k_foldzero(const float* __restrict__ Ww,
                                                  const float* __restrict__ Wb,
                                                  const float* __restrict__ ea,
                                                  float* __restrict__ vkhT,
                                                  float* __restrict__ bl,
                                                  uint_t* __restrict__ zw) {
    int t = threadIdx.x, b = blockIdx.x;
    zw[b * 256 + t] = 0u;
    if (b < HEADS) {
        int k = t, h = b;
        float a = 0.f;
        for (int d = 0; d < HEAD_DIM; ++d)
            a += ea[h * HEAD_DIM + d] * Ww[(size_t)(h * HEAD_DIM + d) * HIDDEN + k];
        vkhT[h * HIDDEN + k] = a;
        if (k == 0) {
            float s = 0.f;
            for (int d = 0; d < HEAD_DIM; ++d)
                s += Wb[h * HEAD_DIM + d] * ea[h * HEAD_DIM + d];
            bl[h] = s;
        }
    }
}

// K2: logits. 256 blocks x 32 nodes; x staged to LDS coalesced.
__global__ __launch_bounds__(256) void k_logits(const float* __restrict__ x,
                                                const float* __restrict__ vkhT,
                                                const float* __restrict__ bl,
                                                float* __restrict__ logit) {
    __shared__ __align__(16) float xs[32 * HIDDEN];
    __shared__ __align__(16) float vs[HEADS * HIDDEN];
    __shared__ float bls[HEADS];
    int t = threadIdx.x, b = blockIdx.x;
    float4* xsv = (float4*)xs;
    const float4* xg = (const float4*)(x + (size_t)b * 32 * HIDDEN);
    #pragma unroll
    for (int i = 0; i < 8; ++i) xsv[i * 256 + t] = xg[i * 256 + t];
    ((float4*)vs)[t] = ((const float4*)vkhT)[t];
    if (t < HEADS) bls[t] = bl[t];
    __syncthreads();
    if (t < 128) {
        int n = t >> 2, h = t & 3;
        const float4* xr = (const float4*)(xs + n * HIDDEN);
        const float4* vr = (const float4*)(vs + h * HIDDEN);
        float acc = bls[h];
        for (int k4 = 0; k4 < HIDDEN / 4; ++k4) {
            float4 xv = xr[k4], vv = vr[k4];
            acc += xv.x * vv.x + xv.y * vv.y + xv.z * vv.z + xv.w * vv.w;
        }
        logit[(b * 32 + n) * HEADS + h] = acc;
    }
}

// K3: histogram counts (int atomics)
__global__ void k_pass1(const int* __restrict__ node_idx, const int* __restrict__ edge_idx,
                        int* __restrict__ seg_size, int* __restrict__ node_cnt) {
    int i = blockIdx.x * 256 + threadIdx.x;
    atomicAdd(&seg_size[edge_idx[i]], 1);
    atomicAdd(&node_cnt[node_idx[i]], 1);
}

// K4: exclusive scans
__global__ __launch_bounds__(256) void k_scan(const int* __restrict__ node_cnt, int* __restrict__ node_ptr,
                                              const int* __restrict__ seg_size, int* __restrict__ edge_ptr) {
    __shared__ int part[256];
    const int* cnt; int* ptr; int n;
    if (blockIdx.x == 0) { cnt = node_cnt; ptr = node_ptr; n = N_NODES; }
    else                 { cnt = seg_size; ptr = edge_ptr; n = NUM_EDGES; }
    int t = threadIdx.x, C = n / 256;
    int s = 0;
    for (int j = 0; j < C; ++j) s += cnt[t * C + j];
    part[t] = s;
    __syncthreads();
    if (t == 0) {
        int run = 0;
        for (int i = 0; i < 256; ++i) { int tmp = part[i]; part[i] = run; run += tmp; }
        ptr[n] = run;
    }
    __syncthreads();
    int run = part[t];
    for (int j = 0; j < C; ++j) { ptr[t * C + j] = run; run += cnt[t * C + j]; }
}

// K5: fill CSRs
__global__ void k_fill(const int* __restrict__ node_idx, const int* __restrict__ edge_idx,
                       const int* __restrict__ node_ptr, const int* __restrict__ edge_ptr,
                       int* __restrict__ node_fill, int* __restrict__ edge_fill,
                       int* __restrict__ node_inc, int* __restrict__ edge_mem) {
    int i = blockIdx.x * 256 + threadIdx.x;
    int n = node_idx[i], e = edge_idx[i];
    int p = node_ptr[n] + atomicAdd(&node_fill[n], 1);
    node_inc[p] = i;
    int q = edge_ptr[e] + atomicAdd(&edge_fill[e], 1);
    edge_mem[q] = n;
}

// K6: seg_sum by edge-parallel gather
__global__ __launch_bounds__(256) void k_seg(const int* __restrict__ edge_ptr,
                                             const int* __restrict__ edge_mem,
                                             const float* __restrict__ logit,
                                             float* __restrict__ seg_sum) {
    int e = blockIdx.x * 256 + threadIdx.x;
    int qb = edge_ptr[e], qe = edge_ptr[e + 1];
    float s0 = 0, s1 = 0, s2 = 0, s3 = 0;
    for (int q = qb; q < qe; ++q) {
        int j = edge_mem[q];
        s0 += __expf(logit[j * 4 + 0]);
        s1 += __expf(logit[j * 4 + 1]);
        s2 += __expf(logit[j * 4 + 2]);
        s3 += __expf(logit[j * 4 + 3]);
    }
    seg_sum[e * 4 + 0] = s0; seg_sum[e * 4 + 1] = s1;
    seg_sum[e * 4 + 2] = s2; seg_sum[e * 4 + 3] = s3;
}

// K7: aw_item[p] = {attn, qb, qe, 0} in node-CSR order
__global__ __launch_bounds__(256) void k_pairs(const int* __restrict__ node_inc,
                                               const int* __restrict__ node_idx,
                                               const int* __restrict__ edge_idx,
                                               const int* __restrict__ edge_ptr,
                                               const float* __restrict__ logit,
                                               const float* __restrict__ seg_sum,
                                               float4* __restrict__ item) {
    int p = blockIdx.x * 256 + threadIdx.x;
    int m = node_inc[p];
    int e = edge_idx[m];
    int qb = edge_ptr[e], qe = edge_ptr[e + 1];
    float a = 0.f;
    if (qe - qb >= 2) {
        int n = node_idx[m];
        float s = 0.f;
        #pragma unroll
        for (int h = 0; h < HEADS; ++h)
            s += __expf(logit[n * HEADS + h]) / seg_sum[e * HEADS + h];
        a = 0.25f * s;
    }
    float4 it;
    it.x = a;
    it.y = __int_as_float(qb);
    it.z = __int_as_float(qe);
    it.w = 0.f;
    item[p] = it;
}

// K8 (fused): every block builds+stores AW row blockIdx.x; blocks 0..511 then
// reuse the same 32KB LDS as the 16-row out0 tile (GEMM+LN) — the VALU work
// runs in the shadow of other blocks' HBM stores. LDS stays 32KB -> 5 blk/CU.
__global__ __launch_bounds__(256) void k_aw_out(const float4* __restrict__ item,
                                                const int* __restrict__ node_ptr,
                                                const int* __restrict__ edge_mem,
                                                const float* __restrict__ x,
                                                const float* __restrict__ out_w,
                                                const float* __restrict__ out_b,
                                                float* __restrict__ AW,
                                                float* __restrict__ out0) {
    __shared__ __align__(16) float buf[N_NODES];   // 32 KB: row, then y[16][260]
    __shared__ float sr[16], mu_s[16], rs_s[16];
    int t = threadIdx.x, w = t >> 6, lane = t & 63;
    int i = blockIdx.x;

    // ---- phase 1: AW row i ----
    float4* rowv = (float4*)buf;
    #pragma unroll
    for (int c = 0; c < 8; ++c) rowv[c * 256 + t] = make_float4(0.f, 0.f, 0.f, 0.f);
    __syncthreads();
    int pb = node_ptr[i], pe = node_ptr[i + 1];
    for (int p = pb + w; p < pe; p += 4) {          // 4 parallel wave chains
        float4 it = item[p];
        float a = it.x;
        if (a != 0.f) {
            int qb = __float_as_int(it.y), qe = __float_as_int(it.z);
            for (int q = qb + lane; q < qe; q += 64)
                atomicAdd(&buf[edge_mem[q]], a);    // LDS atomic
        }
    }
    __syncthreads();
    if (t == 0) buf[i] = 0.f;                       // zero diagonal
    __syncthreads();
    f4v* dst = (f4v*)(AW + (size_t)i * N_NODES);
    #pragma unroll
    for (int c = 0; c < 8; ++c)
        __builtin_nontemporal_store(((const f4v*)rowv)[c * 256 + t], &dst[c * 256 + t]);

    if (i >= 512) return;

    // ---- phase 2: out0 tile rows [i*16, i*16+16) ----
    __syncthreads();                                 // all lanes done reading buf
    float (*y)[260] = (float (*)[260])buf;           // 16*260*4 = 16640 B
    int R = i * 16;
    if (t < 16) {
        int n = R + t;
        int nb = node_ptr[n], ne = node_ptr[n + 1];
        float ws = 0.f;
        for (int p = nb; p < ne; ++p) ws += item[p].x;   // contiguous
        int c = ne - nb; if (c < 1) c = 1;
        sr[t] = ws / (float)c;
    }
    __syncthreads();
    #pragma unroll
    for (int r = 0; r < 16; ++r)
        y[r][t] = sr[r] * x[(size_t)(R + r) * HIDDEN + t];
    __syncthreads();
    float acc[16];
    float bias = out_b[t];
    #pragma unroll
    for (int r = 0; r < 16; ++r) acc[r] = bias;
    const float4* wr4 = (const float4*)(out_w + (size_t)t * HIDDEN);
    for (int j4 = 0; j4 < HIDDEN / 4; ++j4) {
        float4 wv = wr4[j4];
        #pragma unroll
        for (int r = 0; r < 16; ++r) {
            float4 yv = *(const float4*)&y[r][j4 * 4];
            acc[r] += yv.x * wv.x + yv.y * wv.y + yv.z * wv.z + yv.w * wv.w;
        }
    }
    __syncthreads();
    #pragma unroll
    for (int r = 0; r < 16; ++r) y[r][t] = acc[r];
    __syncthreads();
    // wave-parallel LN: wave w reduces rows 4w..4w+3 via shuffles
    #pragma unroll
    for (int rr = 0; rr < 4; ++rr) {
        int r = (w << 2) | rr;
        float v = y[r][lane] + y[r][lane + 64] + y[r][lane + 128] + y[r][lane + 192];
        #pragma unroll
        for (int off = 32; off; off >>= 1) v += __shfl_down(v, off, 64);
        float mu = __shfl(v, 0, 64) * (1.0f / HIDDEN);
        float d0 = y[r][lane] - mu, d1 = y[r][lane + 64] - mu;
        float d2 = y[r][lane + 128] - mu, d3 = y[r][lane + 192] - mu;
        float s2 = d0 * d0 + d1 * d1 + d2 * d2 + d3 * d3;
        #pragma unroll
        for (int off = 32; off; off >>= 1) s2 += __shfl_down(s2, off, 64);
        if (lane == 0) {
            mu_s[r] = mu;
            rs_s[r] = rsqrtf(s2 * (1.0f / HIDDEN) + LN_EPS);
        }
    }
    __syncthreads();
    #pragma unroll
    for (int r = 0; r < 16; ++r)
        out0[(size_t)(R + r) * HIDDEN + t] = (y[r][t] - mu_s[r]) * rs_s[r];
}

extern "C" void kernel_launch(void* const* d_in, const int* in_sizes, int n_in,
                              void* d_out, int out_size, void* d_ws, size_t ws_size,
                              hipStream_t stream) {
    const float* x        = (const float*)d_in[0];
    const int*   node_idx = (const int*)d_in[1];
    const int*   edge_idx = (const int*)d_in[2];
    const float* Ww       = (const float*)d_in[3];
    const float* Wb       = (const float*)d_in[4];
    const float* ea       = (const float*)d_in[5];
    const float* ow       = (const float*)d_in[6];
    const float* ob       = (const float*)d_in[7];
    float* out0 = (float*)d_out;
    float* aw   = out0 + (size_t)N_NODES * HIDDEN;

    char* ws = (char*)d_ws;
    int*    seg_size  = (int*)(ws + OFF_SEGSZ);
    int*    node_cnt  = (int*)(ws + OFF_NCNT);
    int*    node_fill = (int*)(ws + OFF_NFILL);
    int*    edge_fill = (int*)(ws + OFF_EFILL);
    float*  vkhT      = (float*)(ws + OFF_VKH);
    float*  bl        = (float*)(ws + OFF_BL);
    float*  logit     = (float*)(ws + OFF_LOGIT);
    int*    node_ptr  = (int*)(ws + OFF_NPTR);
    int*    edge_ptr  = (int*)(ws + OFF_EPTR);
    float*  seg_sum   = (float*)(ws + OFF_SEGSUM);
    int*    node_inc  = (int*)(ws + OFF_NINC);
    int*    edge_mem  = (int*)(ws + OFF_EMEM);
    float4* item      = (float4*)(ws + OFF_ITEM);

    k_foldzero<<<ZERO_BYTES / 4 / 256, 256, 0, stream>>>(Ww, Wb, ea, vkhT, bl, (uint_t*)ws);
    k_logits<<<N_NODES / 32, 256, 0, stream>>>(x, vkhT, bl, logit);
    k_pass1<<<NUM_INC / 256, 256, 0, stream>>>(node_idx, edge_idx, seg_size, node_cnt);
    k_scan<<<2, 256, 0, stream>>>(node_cnt, node_ptr, seg_size, edge_ptr);
    k_fill<<<NUM_INC / 256, 256, 0, stream>>>(node_idx, edge_idx, node_ptr, edge_ptr,
                                              node_fill, edge_fill, node_inc, edge_mem);
    k_seg<<<NUM_EDGES / 256, 256, 0, stream>>>(edge_ptr, edge_mem, logit, seg_sum);
    k_pairs<<<NUM_INC / 256, 256, 0, stream>>>(node_inc, node_idx, edge_idx, edge_ptr,
                                               logit, seg_sum, item);
    k_aw_out<<<N_NODES, 256, 0, stream>>>(item, node_ptr, edge_mem, x, ow, ob, aw, out0);
}